// Round 1
// baseline (364.434 us; speedup 1.0000x reference)
//
#include <hip/hip_runtime.h>
#include <math.h>

#define CLS 1000          // number of classes
#define VEC_PER_ROW 250   // 1000 / 4 float4s per row
#define BETA 3.0f

// ---------------------------------------------------------------------------
// Kernel A: one wave (64 lanes) per row. Each lane keeps its <=16 elements in
// registers (4x float4). Pass 1: max + argmax (wave shuffle reduce).
// Pass 2 (registers, no re-read): sum of exp(x - M) and the target logit.
// Lane 0 writes logp_target, pred, and scatters +1 into the confusion matrix.
// ---------------------------------------------------------------------------
__global__ __launch_bounds__(256) void softmax_pass(
    const float* __restrict__ outputs,
    const int* __restrict__ targets,
    float* __restrict__ cm,          // [CLS, CLS]
    float* __restrict__ logp,        // [B]
    int* __restrict__ pred,          // [B]
    int B)
{
    const int wave = threadIdx.x >> 6;
    const int lane = threadIdx.x & 63;
    const int row  = blockIdx.x * 4 + wave;
    if (row >= B) return;

    const float4* rp = (const float4*)(outputs + (size_t)row * CLS);

    float4 r[4];
#pragma unroll
    for (int k = 0; k < 4; ++k) {
        const int j = lane + 64 * k;
        if (j < VEC_PER_ROW) {
            r[k] = rp[j];
        } else {
            r[k] = make_float4(-INFINITY, -INFINITY, -INFINITY, -INFINITY);
        }
    }

    // per-lane max + argmax (ascending idx order -> first-max tie-break)
    float vmax = -INFINITY;
    int   vidx = 0x7fffffff;
#pragma unroll
    for (int k = 0; k < 4; ++k) {
        const int base = (lane + 64 * k) * 4;
        const float* f = (const float*)&r[k];
#pragma unroll
        for (int c = 0; c < 4; ++c) {
            const float x = f[c];
            if (x > vmax) { vmax = x; vidx = base + c; }
        }
    }

    // wave reduce max+argmax (64 lanes, 6 butterfly steps)
#pragma unroll
    for (int off = 32; off; off >>= 1) {
        const float ov = __shfl_xor(vmax, off);
        const int   oi = __shfl_xor(vidx, off);
        if (ov > vmax || (ov == vmax && oi < vidx)) { vmax = ov; vidx = oi; }
    }

    const int t = targets[row];

    // sum exp(x - M) and grab target logit from registers
    float S  = 0.0f;
    float xt = 0.0f;
#pragma unroll
    for (int k = 0; k < 4; ++k) {
        const int base = (lane + 64 * k) * 4;
        const float* f = (const float*)&r[k];
#pragma unroll
        for (int c = 0; c < 4; ++c) {
            const float x = f[c];
            S += __expf(x - vmax);        // tail lanes: exp(-inf) = 0
            if (base + c == t) xt = x;    // tail idx >= 1000 never matches
        }
    }
#pragma unroll
    for (int off = 32; off; off >>= 1) {
        S  += __shfl_xor(S, off);
        xt += __shfl_xor(xt, off);
    }

    if (lane == 0) {
        logp[row] = xt - vmax - logf(S);
        pred[row] = vidx;
        atomicAdd(&cm[(size_t)t * CLS + vidx], 1.0f);
    }
}

// ---------------------------------------------------------------------------
// Kernel B: scale[t] = BETA / max(1, sum_p cm[t, p]).  One wave per row.
// ---------------------------------------------------------------------------
__global__ __launch_bounds__(256) void row_scale(
    const float* __restrict__ cm,
    float* __restrict__ scale)
{
    const int wave = threadIdx.x >> 6;
    const int lane = threadIdx.x & 63;
    const int row  = blockIdx.x * 4 + wave;
    if (row >= CLS) return;

    const float4* rp = (const float4*)(cm + (size_t)row * CLS);
    float s = 0.0f;
    for (int j = lane; j < VEC_PER_ROW; j += 64) {
        const float4 v = rp[j];
        s += v.x + v.y + v.z + v.w;
    }
#pragma unroll
    for (int off = 32; off; off >>= 1) s += __shfl_xor(s, off);
    if (lane == 0) scale[row] = BETA / fmaxf(1.0f, s);
}

// ---------------------------------------------------------------------------
// Kernel C: loss = -(1/B) * sum_b logp[b] * cm[t_b, p_b] * scale[t_b]
// ---------------------------------------------------------------------------
__global__ __launch_bounds__(256) void finalize(
    const float* __restrict__ cm,
    const float* __restrict__ scale,
    const float* __restrict__ logp,
    const int* __restrict__ pred,
    const int* __restrict__ targets,
    float* __restrict__ out,
    int B)
{
    const int i = blockIdx.x * 256 + threadIdx.x;
    float v = 0.0f;
    if (i < B) {
        const int t = targets[i];
        const int p = pred[i];
        v = logp[i] * cm[(size_t)t * CLS + p] * scale[t];
    }
    const int lane = threadIdx.x & 63;
    const int wave = threadIdx.x >> 6;
#pragma unroll
    for (int off = 32; off; off >>= 1) v += __shfl_xor(v, off);

    __shared__ float ssum[4];
    if (lane == 0) ssum[wave] = v;
    __syncthreads();
    if (threadIdx.x == 0) {
        const float s = ssum[0] + ssum[1] + ssum[2] + ssum[3];
        atomicAdd(out, -s / (float)B);
    }
}

extern "C" void kernel_launch(void* const* d_in, const int* in_sizes, int n_in,
                              void* d_out, int out_size, void* d_ws, size_t ws_size,
                              hipStream_t stream)
{
    const float* outputs     = (const float*)d_in[0];
    const int*   targets     = (const int*)d_in[1];
    const float* cost_matrix = (const float*)d_in[2];
    const int B = in_sizes[1];

    // workspace layout (all 16B aligned)
    char* ws = (char*)d_ws;
    float* cm    = (float*)(ws);                              // 4,000,000 B
    float* logp  = (float*)(ws + 4000000);                    //   B*4 B
    int*   pred  = (int*)  (ws + 4000000 + (size_t)B * 4);    //   B*4 B
    float* scale = (float*)(ws + 4000000 + (size_t)B * 8);    //   4000 B

    // init: out = 0, cm = cost_matrix input
    hipMemsetAsync(d_out, 0, sizeof(float), stream);
    hipMemcpyAsync(cm, cost_matrix, (size_t)CLS * CLS * sizeof(float),
                   hipMemcpyDeviceToDevice, stream);

    softmax_pass<<<(B + 3) / 4, 256, 0, stream>>>(outputs, targets, cm, logp, pred, B);
    row_scale<<<(CLS + 3) / 4, 256, 0, stream>>>(cm, scale);
    finalize<<<(B + 255) / 256, 256, 0, stream>>>(cm, scale, logp, pred, targets,
                                                  (float*)d_out, B);
}

// Round 2
// 361.268 us; speedup vs baseline: 1.0088x; 1.0088x over previous
//
#include <hip/hip_runtime.h>
#include <math.h>

#define CLS 1000          // number of classes
#define VEC_PER_ROW 250   // 1000 / 4 float4s per row
#define BETA 3.0f
#define NPART 256         // partial sums for final reduction

// ---------------------------------------------------------------------------
// Kernel A: one wave (64 lanes) per row, 4 rows per 256-thread block.
// Each lane holds its <=16 row elements in registers (4x float4).
// Pass 1 (registers): row max via fmaxf tree + 6-step butterfly.
// Pass 2 (registers): sum exp(x-m); argmax = min index where x==m
//   (first-occurrence tie-break, matching jnp.argmax).
// Lane 0: loads target logit directly (row is L2-hot), writes logp/pred,
// scatters +1 into the confusion matrix.
// ---------------------------------------------------------------------------
__global__ __launch_bounds__(256) void softmax_pass(
    const float* __restrict__ outputs,
    const int* __restrict__ targets,
    float* __restrict__ cm,          // [CLS, CLS]
    float* __restrict__ logp,        // [B]
    int* __restrict__ pred,          // [B]
    int B)
{
    const int wave = threadIdx.x >> 6;
    const int lane = threadIdx.x & 63;
    const int row  = blockIdx.x * 4 + wave;
    if (row >= B) return;

    const float4* rp = (const float4*)(outputs + (size_t)row * CLS);

    float4 r[4];
#pragma unroll
    for (int k = 0; k < 4; ++k) {
        const int j = lane + 64 * k;
        if (j < VEC_PER_ROW) {
            r[k] = rp[j];
        } else {
            r[k] = make_float4(-INFINITY, -INFINITY, -INFINITY, -INFINITY);
        }
    }

    // pass 1: max only (fmax tree -> v_max3 friendly)
    float m = -INFINITY;
#pragma unroll
    for (int k = 0; k < 4; ++k)
        m = fmaxf(m, fmaxf(fmaxf(r[k].x, r[k].y), fmaxf(r[k].z, r[k].w)));
#pragma unroll
    for (int off = 32; off; off >>= 1)
        m = fmaxf(m, __shfl_xor(m, off));

    // pass 2: exp-sum + equality argmax (min idx where x == m)
    float S  = 0.0f;
    int  idx = 0x7fffffff;
#pragma unroll
    for (int k = 0; k < 4; ++k) {
        const int base = (lane + 64 * k) * 4;
        const float* f = (const float*)&r[k];
#pragma unroll
        for (int c = 0; c < 4; ++c) {
            const float x = f[c];
            S += __expf(x - m);                    // tail: exp(-inf) = 0
            if (x == m) idx = min(idx, base + c);  // tail: -inf != m
        }
    }
#pragma unroll
    for (int off = 32; off; off >>= 1) {
        S   += __shfl_xor(S, off);
        idx  = min(idx, __shfl_xor(idx, off));
    }

    if (lane == 0) {
        const int t   = targets[row];
        const float xt = outputs[(size_t)row * CLS + t];  // L2-hot gather
        logp[row] = xt - m - __logf(S);
        pred[row] = idx;
        atomicAdd(&cm[(size_t)t * CLS + idx], 1.0f);
    }
}

// ---------------------------------------------------------------------------
// Kernel B: scale[t] = BETA / max(1, sum_p cm[t, p]).  One wave per row.
// ---------------------------------------------------------------------------
__global__ __launch_bounds__(256) void row_scale(
    const float* __restrict__ cm,
    float* __restrict__ scale)
{
    const int wave = threadIdx.x >> 6;
    const int lane = threadIdx.x & 63;
    const int row  = blockIdx.x * 4 + wave;
    if (row >= CLS) return;

    const float4* rp = (const float4*)(cm + (size_t)row * CLS);
    float s = 0.0f;
    for (int j = lane; j < VEC_PER_ROW; j += 64) {
        const float4 v = rp[j];
        s += v.x + v.y + v.z + v.w;
    }
#pragma unroll
    for (int off = 32; off; off >>= 1) s += __shfl_xor(s, off);
    if (lane == 0) scale[row] = BETA / fmaxf(1.0f, s);
}

// ---------------------------------------------------------------------------
// Kernel C1: per-block partials of sum_b logp[b] * cm[t_b, p_b] * scale[t_b]
// ---------------------------------------------------------------------------
__global__ __launch_bounds__(256) void finalize_partial(
    const float* __restrict__ cm,
    const float* __restrict__ scale,
    const float* __restrict__ logp,
    const int* __restrict__ pred,
    const int* __restrict__ targets,
    float* __restrict__ partial,     // [NPART]
    int B)
{
    float v = 0.0f;
    for (int i = blockIdx.x * 256 + threadIdx.x; i < B; i += NPART * 256) {
        const int t = targets[i];
        const int p = pred[i];
        v += logp[i] * cm[(size_t)t * CLS + p] * scale[t];
    }
    const int lane = threadIdx.x & 63;
    const int wave = threadIdx.x >> 6;
#pragma unroll
    for (int off = 32; off; off >>= 1) v += __shfl_xor(v, off);

    __shared__ float ssum[4];
    if (lane == 0) ssum[wave] = v;
    __syncthreads();
    if (threadIdx.x == 0)
        partial[blockIdx.x] = ssum[0] + ssum[1] + ssum[2] + ssum[3];
}

// ---------------------------------------------------------------------------
// Kernel C2: reduce NPART partials, write -sum/B. No atomics, no memset.
// ---------------------------------------------------------------------------
__global__ __launch_bounds__(256) void finalize_reduce(
    const float* __restrict__ partial,
    float* __restrict__ out,
    int B)
{
    float v = (threadIdx.x < NPART) ? partial[threadIdx.x] : 0.0f;
    const int lane = threadIdx.x & 63;
    const int wave = threadIdx.x >> 6;
#pragma unroll
    for (int off = 32; off; off >>= 1) v += __shfl_xor(v, off);

    __shared__ float ssum[4];
    if (lane == 0) ssum[wave] = v;
    __syncthreads();
    if (threadIdx.x == 0)
        out[0] = -(ssum[0] + ssum[1] + ssum[2] + ssum[3]) / (float)B;
}

extern "C" void kernel_launch(void* const* d_in, const int* in_sizes, int n_in,
                              void* d_out, int out_size, void* d_ws, size_t ws_size,
                              hipStream_t stream)
{
    const float* outputs     = (const float*)d_in[0];
    const int*   targets     = (const int*)d_in[1];
    const float* cost_matrix = (const float*)d_in[2];
    const int B = in_sizes[1];

    // workspace layout (16B aligned)
    char* ws = (char*)d_ws;
    float* cm      = (float*)(ws);                              // 4,000,000 B
    float* logp    = (float*)(ws + 4000000);                    // B*4
    int*   pred    = (int*)  (ws + 4000000 + (size_t)B * 4);    // B*4
    float* scale   = (float*)(ws + 4000000 + (size_t)B * 8);    // 4000 B
    float* partial = (float*)(ws + 4000000 + (size_t)B * 8 + 4096); // NPART*4

    // cm = cost_matrix input (scatter target)
    hipMemcpyAsync(cm, cost_matrix, (size_t)CLS * CLS * sizeof(float),
                   hipMemcpyDeviceToDevice, stream);

    softmax_pass<<<(B + 3) / 4, 256, 0, stream>>>(outputs, targets, cm, logp, pred, B);
    row_scale<<<(CLS + 3) / 4, 256, 0, stream>>>(cm, scale);
    finalize_partial<<<NPART, 256, 0, stream>>>(cm, scale, logp, pred, targets,
                                                partial, B);
    finalize_reduce<<<1, 256, 0, stream>>>(partial, (float*)d_out, B);
}